// Round 3
// baseline (242.130 us; speedup 1.0000x reference)
//
#include <hip/hip_runtime.h>

// PointPillarScatter: out[b][c][y][x] = feat[p][c] where coords[p]=(x,y,b), else 0.
// Strategy: build flat->pillar map in ws, then one gather pass writes the whole
// output exactly once. Each thread owns 4 consecutive x-cells and emits 64
// nontemporal float4 stores (1 KB per wave-instruction, fully coalesced),
// fusing the zero-fill with the scatter.

#define C_CH 64

// Native Clang vector type: __builtin_nontemporal_store requires a vector of
// scalars, not HIP's HIP_vector_type<float,4> class.
typedef float nat_float4 __attribute__((ext_vector_type(4)));

__global__ void build_map_kernel(const int* __restrict__ coords, int n_pillars,
                                 const int* __restrict__ nx_p,
                                 const int* __restrict__ ny_p,
                                 int* __restrict__ map) {
    int p = blockIdx.x * blockDim.x + threadIdx.x;
    if (p >= n_pillars) return;
    const int nx = nx_p[0];
    const int ny = ny_p[0];
    const int x = coords[3 * p + 0];
    const int y = coords[3 * p + 1];
    const int b = coords[3 * p + 2];
    const long long m = (long long)b * (long long)(nx * ny) + (long long)y * nx + x;
    map[m] = p;
}

// One thread per 4 consecutive (x) cells. Reads one int4 of the map, then for
// each of the 64 channels builds a float4 (zeros or masked gathers from the
// L2-resident feature rows) and stores it nontemporally.
// All float4-granular output indices fit in 32 bits (max ~13.7M).
__global__ void __launch_bounds__(256) gather64x4_kernel(
        const float* __restrict__ feat,
        const int* __restrict__ map,
        const int* __restrict__ nx_p,
        const int* __restrict__ ny_p,
        float* __restrict__ out, int n_cell4) {
    const int t = blockIdx.x * blockDim.x + threadIdx.x;
    if (t >= n_cell4) return;
    const int plane4 = (nx_p[0] * ny_p[0]) >> 2;   // uniform
    const int b = t / plane4;
    const int rem4 = t - b * plane4;

    const int4 pv = ((const int4*)map)[t];

    const float* __restrict__ f0 = feat + (long long)pv.x * C_CH;
    const float* __restrict__ f1 = feat + (long long)pv.y * C_CH;
    const float* __restrict__ f2 = feat + (long long)pv.z * C_CH;
    const float* __restrict__ f3 = feat + (long long)pv.w * C_CH;

    nat_float4* __restrict__ out4 = (nat_float4*)out;
    const int base = b * C_CH * plane4 + rem4;     // fits in int (< 2^24)

#pragma unroll 8
    for (int c = 0; c < C_CH; ++c) {
        nat_float4 v = {0.f, 0.f, 0.f, 0.f};
        if (pv.x >= 0) v.x = f0[c];
        if (pv.y >= 0) v.y = f1[c];
        if (pv.z >= 0) v.z = f2[c];
        if (pv.w >= 0) v.w = f3[c];
        __builtin_nontemporal_store(v, out4 + base + c * plane4);
    }
}

// Fallback: direct scatter after zeroing the output (used only if ws is too
// small for the map, C != 64, or the plane isn't float4-divisible).
__global__ void direct_scatter_kernel(const float* __restrict__ feat,
                                      const int* __restrict__ coords,
                                      int n_pillars, int C,
                                      const int* __restrict__ nx_p,
                                      const int* __restrict__ ny_p,
                                      float* __restrict__ out) {
    const long long t = (long long)blockIdx.x * blockDim.x + threadIdx.x;
    if (t >= (long long)n_pillars * C) return;
    const int p = (int)(t / C);
    const int c = (int)(t - (long long)p * C);
    const int nx = nx_p[0];
    const int ny = ny_p[0];
    const int x = coords[3 * p + 0];
    const int y = coords[3 * p + 1];
    const int b = coords[3 * p + 2];
    const int plane = nx * ny;
    const size_t o = ((size_t)b * C + c) * (size_t)plane + (size_t)y * nx + x;
    out[o] = feat[(size_t)p * C + c];
}

extern "C" void kernel_launch(void* const* d_in, const int* in_sizes, int n_in,
                              void* d_out, int out_size, void* d_ws, size_t ws_size,
                              hipStream_t stream) {
    const float* feat   = (const float*)d_in[0];
    const int*   coords = (const int*)d_in[1];
    // d_in[2] = batch_size, d_in[3] = nx, d_in[4] = ny — device-resident
    // scalars, read inside the kernels where needed.
    const int* nx_p = (const int*)d_in[3];
    const int* ny_p = (const int*)d_in[4];
    float* out = (float*)d_out;

    const int n_pillars = in_sizes[1] / 3;
    const int C = in_sizes[0] / n_pillars;
    const int n_map = out_size / C;                 // B * NY * NX
    const size_t map_bytes = (size_t)n_map * sizeof(int);

    if (C == C_CH && (n_map & 3) == 0 && ws_size >= map_bytes) {
        int* map = (int*)d_ws;
        // 0xFF bytes -> every map entry == -1
        (void)hipMemsetAsync(map, 0xFF, map_bytes, stream);
        build_map_kernel<<<(n_pillars + 255) / 256, 256, 0, stream>>>(
            coords, n_pillars, nx_p, ny_p, map);
        const int n_cell4 = n_map >> 2;
        gather64x4_kernel<<<(n_cell4 + 255) / 256, 256, 0, stream>>>(
            feat, map, nx_p, ny_p, out, n_cell4);
    } else {
        (void)hipMemsetAsync(out, 0, (size_t)out_size * sizeof(float), stream);
        const long long total = (long long)n_pillars * C;
        direct_scatter_kernel<<<(unsigned)((total + 255) / 256), 256, 0, stream>>>(
            feat, coords, n_pillars, C, nx_p, ny_p, out);
    }
}